// Round 3
// baseline (129.882 us; speedup 1.0000x reference)
//
#include <hip/hip_runtime.h>
#include <hip/hip_bf16.h>

// Sizes (fixed by the reference)
#define BATCH 2
#define SEQ   4096
#define DIM   256
#define HEADS 8
#define HDIM  32
#define M_ROWS (BATCH * SEQ)   // 8192

typedef short bf16x8 __attribute__((ext_vector_type(8)));
typedef unsigned short u16x8 __attribute__((ext_vector_type(8)));
typedef float f32x4 __attribute__((ext_vector_type(4)));

static __device__ inline unsigned short f2bf(float x) {
  union { float f; unsigned u; } v; v.f = x;
  unsigned r = v.u + 0x7FFF + ((v.u >> 16) & 1);   // round-nearest-even
  return (unsigned short)(r >> 16);
}

// ---------------------------------------------------------------------------
// K0: prep — Wt[n][k] = bf16(Wcat[k][n]), n in [0,512) over [Wl|Wr].
// ---------------------------------------------------------------------------
__global__ __launch_bounds__(256) void k_prep(const float* __restrict__ Wl,
                                              const float* __restrict__ Wr,
                                              unsigned short* __restrict__ Wt) {
  __shared__ float tile[32][33];
  const int k0 = blockIdx.x * 32;
  const int n0 = blockIdx.y * 32;
  const int t = threadIdx.x;
  const float* W = (n0 < 256) ? Wl : Wr;
  const int nb = n0 & 255;
  {
    const int r = t >> 3;            // k-local
    const int c = (t & 7) * 4;       // n-local
    const float4 v = *(const float4*)(&W[(size_t)(k0 + r) * DIM + nb + c]);
    tile[r][c + 0] = v.x; tile[r][c + 1] = v.y;
    tile[r][c + 2] = v.z; tile[r][c + 3] = v.w;
  }
  __syncthreads();
  {
    const int nl = t >> 3;           // n-local
    const int kl = (t & 7) * 4;      // k-local
    ushort4 o;
    o.x = f2bf(tile[kl + 0][nl]); o.y = f2bf(tile[kl + 1][nl]);
    o.z = f2bf(tile[kl + 2][nl]); o.w = f2bf(tile[kl + 3][nl]);
    *(ushort4*)(&Wt[(size_t)(n0 + nl) * DIM + k0 + kl]) = o;
  }
}

// ---------------------------------------------------------------------------
// K1: fused MFMA GEMM + head-score epilogue.
// Grid 256 blocks x 512 threads. Block (bm, isR): 64 rows x 256 cols of
// (isR ? fr : fl). 8 waves, one head (32 cols) each; 16x16x32 bf16 MFMA.
// fl is never written to global: its only consumer is msl (computed here).
// fr-blocks also write sr (per-head scores) and fr itself.
// ---------------------------------------------------------------------------
__global__ __launch_bounds__(512) void k_gemm_fused(
    const float* __restrict__ A, const unsigned short* __restrict__ Wt,
    const float* __restrict__ a_l, const float* __restrict__ a_r,
    float* __restrict__ fr, float* __restrict__ sr,
    float* __restrict__ msl, float* __restrict__ msr) {
  __shared__ unsigned short As[64 * 32];    // 4 KB
  __shared__ unsigned short Bs[256 * 32];   // 16 KB
  __shared__ float red[64][8];              // per-row per-head sums

  const int bid = blockIdx.x;
  const int isR = bid & 1;
  const int bm  = bid >> 1;       // 128 row tiles of 64
  const int m0 = bm * 64;
  const int n0 = isR * 256;       // Wt row offset (0: W_l, 256: W_r)

  const int t = threadIdx.x;
  const int lane = t & 63;
  const int wid = t >> 6;         // wave = head 0..7 (cols wid*32..+32)

  f32x4 acc[4][2];
  #pragma unroll
  for (int i = 0; i < 4; ++i)
    #pragma unroll
    for (int j = 0; j < 2; ++j) acc[i][j] = (f32x4){0.f, 0.f, 0.f, 0.f};

  for (int k0 = 0; k0 < DIM; k0 += 32) {
    // stage A: 64 rows x 32 k (f32 -> bf16), threads 0..255
    if (t < 256) {
      const int row = t >> 2;
      const int kc = t & 3;
      const int slot = kc ^ ((row >> 1) & 3);
      const float4 a0 = *(const float4*)(&A[(size_t)(m0 + row) * DIM + k0 + kc * 8]);
      const float4 a1 = *(const float4*)(&A[(size_t)(m0 + row) * DIM + k0 + kc * 8 + 4]);
      u16x8 pa;
      pa[0] = f2bf(a0.x); pa[1] = f2bf(a0.y); pa[2] = f2bf(a0.z); pa[3] = f2bf(a0.w);
      pa[4] = f2bf(a1.x); pa[5] = f2bf(a1.y); pa[6] = f2bf(a1.z); pa[7] = f2bf(a1.w);
      *(u16x8*)((char*)As + row * 64 + slot * 16) = pa;
    }
    // stage B: 256 rows x 32 k bf16, all 512 threads, 2 tasks each
    #pragma unroll
    for (int p = 0; p < 2; ++p) {
      const int task = t + p * 512;
      const int row = task >> 2;      // 0..255
      const int kc = task & 3;
      const int slot = kc ^ ((row >> 1) & 3);
      const u16x8 pb = *(const u16x8*)(&Wt[(size_t)(n0 + row) * DIM + k0 + kc * 8]);
      *(u16x8*)((char*)Bs + row * 64 + slot * 16) = pb;
    }
    __syncthreads();

    bf16x8 af[4], bfr[2];
    #pragma unroll
    for (int mr = 0; mr < 4; ++mr) {
      const int ra = mr * 16 + (lane & 15);
      const int sl = (lane >> 4) ^ ((ra >> 1) & 3);
      af[mr] = *(const bf16x8*)((const char*)As + ra * 64 + sl * 16);
    }
    #pragma unroll
    for (int nr = 0; nr < 2; ++nr) {
      const int cb = wid * 32 + nr * 16 + (lane & 15);
      const int sl = (lane >> 4) ^ ((cb >> 1) & 3);
      bfr[nr] = *(const bf16x8*)((const char*)Bs + cb * 64 + sl * 16);
    }
    #pragma unroll
    for (int mr = 0; mr < 4; ++mr)
      #pragma unroll
      for (int nr = 0; nr < 2; ++nr)
        acc[mr][nr] = __builtin_amdgcn_mfma_f32_16x16x32_bf16(af[mr], bfr[nr], acc[mr][nr], 0, 0, 0);
    __syncthreads();
  }

  // epilogue: per-head score sums. C/D: col=lane&15 (within 16), row=(lane>>4)*4+r.
  const float* av = isR ? a_r : a_l;
  const int b = m0 >> 12;
  const int nbase = m0 & 4095;

  #pragma unroll
  for (int mr = 0; mr < 4; ++mr) {
    #pragma unroll
    for (int r = 0; r < 4; ++r) {
      float p = 0.f;
      #pragma unroll
      for (int nr = 0; nr < 2; ++nr) {
        float x = acc[mr][nr][r];
        x = x >= 0.f ? x : 0.01f * x;
        p = fmaf(x, av[nr * 16 + (lane & 15)], p);
      }
      #pragma unroll
      for (int o = 1; o < 16; o <<= 1) p += __shfl_xor(p, o, 16);
      if ((lane & 15) == 0) {
        const int rl = mr * 16 + (lane >> 4) * 4 + r;
        red[rl][wid] = p;
        if (isR) sr[((size_t)(b * HEADS + wid)) * SEQ + nbase + rl] = p;
      }
    }
  }
  __syncthreads();
  if (t < 64) {
    float s = 0.f;
    #pragma unroll
    for (int h2 = 0; h2 < 8; ++h2) s += red[t][h2];
    (isR ? msr : msl)[m0 + t] = s * 0.125f;
  }
  if (isR) {
    #pragma unroll
    for (int mr = 0; mr < 4; ++mr)
      #pragma unroll
      for (int nr = 0; nr < 2; ++nr) {
        const int col = wid * 32 + nr * 16 + (lane & 15);
        #pragma unroll
        for (int r = 0; r < 4; ++r) {
          const int row = m0 + mr * 16 + (lane >> 4) * 4 + r;
          fr[(size_t)row * DIM + col] = acc[mr][nr][r];
        }
      }
  }
}

// ---------------------------------------------------------------------------
// K2: fused softmax + context + partial fh. One block per (b,h), 16 blocks.
// fhp[b,h,:] = (sum_j softmax(sr[b,h,:])_j * fr[b,j,h*32:(h+1)*32]) @ Wf[h*32:,:]
// ---------------------------------------------------------------------------
__global__ __launch_bounds__(256) void k_smctx(const float* __restrict__ sr,
                                               const float* __restrict__ fr,
                                               const float* __restrict__ Wf,
                                               float* __restrict__ fhp) {
  const int bh = blockIdx.x;
  const int b = bh >> 3, h = bh & 7;
  const int t = threadIdx.x;
  __shared__ float wsm[SEQ];                 // 16 KB
  __shared__ float r1[4], r2[4];
  const float* s = sr + (size_t)bh * SEQ;

  float v[16];
  float mx = -3.4e38f;
  #pragma unroll
  for (int q = 0; q < 16; ++q) { v[q] = s[q * 256 + t]; mx = fmaxf(mx, v[q]); }
  #pragma unroll
  for (int o = 32; o > 0; o >>= 1) mx = fmaxf(mx, __shfl_xor(mx, o, 64));
  if ((t & 63) == 0) r1[t >> 6] = mx;
  __syncthreads();
  mx = fmaxf(fmaxf(r1[0], r1[1]), fmaxf(r1[2], r1[3]));
  float sum = 0.f;
  #pragma unroll
  for (int q = 0; q < 16; ++q) { v[q] = expf(v[q] - mx); sum += v[q]; }
  #pragma unroll
  for (int o = 32; o > 0; o >>= 1) sum += __shfl_xor(sum, o, 64);
  if ((t & 63) == 0) r2[t >> 6] = sum;
  __syncthreads();
  sum = r2[0] + r2[1] + r2[2] + r2[3];
  const float inv = 1.0f / sum;
  #pragma unroll
  for (int q = 0; q < 16; ++q) wsm[q * 256 + t] = v[q] * inv;
  __syncthreads();

  // context: c[d] = sum_j w[j] * fr[b,j,h*32+d]
  const int d = t & 31, jg = t >> 5;
  const float* frb = fr + (size_t)b * SEQ * DIM + h * HDIM + d;
  float c0 = 0.f, c1 = 0.f;
  for (int j = jg; j < SEQ; j += 16) {
    c0 = fmaf(wsm[j],     frb[(size_t)j * DIM], c0);
    c1 = fmaf(wsm[j + 8], frb[(size_t)(j + 8) * DIM], c1);
  }
  __shared__ float cred[8][32];
  __shared__ float c_s[32];
  cred[jg][d] = c0 + c1;
  __syncthreads();
  if (t < 32) {
    float sc = 0.f;
    #pragma unroll
    for (int g2 = 0; g2 < 8; ++g2) sc += cred[g2][t];
    c_s[t] = sc;
  }
  __syncthreads();
  // partial fh: fhp[bh][t] = sum_d c[d] * Wf[h*32+d][t]
  float a2 = 0.f;
  #pragma unroll 8
  for (int dd = 0; dd < HDIM; ++dd)
    a2 = fmaf(c_s[dd], Wf[(size_t)(h * HDIM + dd) * DIM + t], a2);
  fhp[(size_t)bh * DIM + t] = a2;
}

// ---------------------------------------------------------------------------
// K3: fused LayerNorm(h + sum_h fhp) -> out[0:8192*256]  and
//     attn[b,i,j] = msl[b,i] + msr[b,j] -> out tail. One block per row.
// ---------------------------------------------------------------------------
__global__ __launch_bounds__(256) void k_ln_attn(const float* __restrict__ h,
                                                 const float* __restrict__ fhp,
                                                 const float* __restrict__ g,
                                                 const float* __restrict__ bb,
                                                 const float* __restrict__ msl,
                                                 const float* __restrict__ msr,
                                                 float* __restrict__ out,
                                                 float* __restrict__ attn) {
  const int row = blockIdx.x;
  const int b = row >> 12;
  const int t = threadIdx.x;
  float fh = 0.f;
  #pragma unroll
  for (int h2 = 0; h2 < 8; ++h2) fh += fhp[(size_t)(b * HEADS + h2) * DIM + t];
  const float x = h[(size_t)row * DIM + t] + fh;
  float s1 = x, s2 = x * x;
  #pragma unroll
  for (int o = 32; o > 0; o >>= 1) {
    s1 += __shfl_xor(s1, o, 64);
    s2 += __shfl_xor(s2, o, 64);
  }
  __shared__ float r1[4], r2[4];
  if ((t & 63) == 0) { r1[t >> 6] = s1; r2[t >> 6] = s2; }
  __syncthreads();
  s1 = r1[0] + r1[1] + r1[2] + r1[3];
  s2 = r2[0] + r2[1] + r2[2] + r2[3];
  const float mu = s1 * (1.f / 256.f);
  const float var = s2 * (1.f / 256.f) - mu * mu;
  const float rs = rsqrtf(var + 1e-5f);
  out[(size_t)row * DIM + t] = (x - mu) * rs * g[t] + bb[t];

  // attn row: streaming non-temporal stores
  const float v = msl[row];
  const f32x4* mr4 = (const f32x4*)(msr + ((size_t)b << 12));
  f32x4* dst = (f32x4*)(attn + ((size_t)row << 12));
  #pragma unroll
  for (int q = 0; q < 4; ++q) {
    f32x4 m4 = mr4[q * 256 + t];
    __builtin_nontemporal_store(m4 + v, &dst[q * 256 + t]);
  }
}

// ---------------------------------------------------------------------------
extern "C" void kernel_launch(void* const* d_in, const int* in_sizes, int n_in,
                              void* d_out, int out_size, void* d_ws, size_t ws_size,
                              hipStream_t stream) {
  const float* h  = (const float*)d_in[0];
  const float* Wl = (const float*)d_in[1];
  const float* Wr = (const float*)d_in[2];
  const float* al = (const float*)d_in[3];
  const float* ar = (const float*)d_in[4];
  const float* Wf = (const float*)d_in[5];
  const float* g  = (const float*)d_in[6];
  const float* bb = (const float*)d_in[7];
  float* out = (float*)d_out;
  float* ws  = (float*)d_ws;

  float* fr  = ws;                                   // 2,097,152 f32
  float* srs = fr + (size_t)M_ROWS * DIM;            // 65,536
  float* msl = srs + BATCH * HEADS * SEQ;            // 8,192
  float* msr = msl + M_ROWS;                         // 8,192
  float* fhp = msr + M_ROWS;                         // 4,096
  unsigned short* Wt = (unsigned short*)(fhp + BATCH * HEADS * DIM); // 512*256 u16

  k_prep<<<dim3(8, 16), 256, 0, stream>>>(Wl, Wr, Wt);
  k_gemm_fused<<<256, 512, 0, stream>>>(h, Wt, al, ar, fr, srs, msl, msr);
  k_smctx<<<BATCH * HEADS, 256, 0, stream>>>(srs, fr, Wf, fhp);
  k_ln_attn<<<M_ROWS, 256, 0, stream>>>(h, fhp, g, bb, msl, msr,
                                        out, out + (size_t)M_ROWS * DIM);
}

// Round 4
// 56.975 us; speedup vs baseline: 2.2796x; 2.2796x over previous
//
#include <hip/hip_runtime.h>
#include <hip/hip_bf16.h>

// Sizes (fixed by the reference)
#define BATCH 2
#define SEQ   4096
#define DIM   256
#define HEADS 8
#define HDIM  32
#define M_ROWS (BATCH * SEQ)   // 8192
#define JCHUNK 32
#define NCHUNK (SEQ / JCHUNK)  // 128 chunks per batch

typedef short bf16x8 __attribute__((ext_vector_type(8)));
typedef unsigned short u16x8 __attribute__((ext_vector_type(8)));
typedef float f32x4 __attribute__((ext_vector_type(4)));

static __device__ inline unsigned short f2bf(float x) {
  union { float f; unsigned u; } v; v.f = x;
  unsigned r = v.u + 0x7FFF + ((v.u >> 16) & 1);   // round-nearest-even
  return (unsigned short)(r >> 16);
}

// ---------------------------------------------------------------------------
// K0: prep — Wt[n][k] = bf16(Wcat[k][n]), n in [0,512) over [Wl|Wr].
// ---------------------------------------------------------------------------
__global__ __launch_bounds__(256) void k_prep(const float* __restrict__ Wl,
                                              const float* __restrict__ Wr,
                                              unsigned short* __restrict__ Wt) {
  __shared__ float tile[32][33];
  const int k0 = blockIdx.x * 32;
  const int n0 = blockIdx.y * 32;
  const int t = threadIdx.x;
  const float* W = (n0 < 256) ? Wl : Wr;
  const int nb = n0 & 255;
  {
    const int r = t >> 3;            // k-local
    const int c = (t & 7) * 4;       // n-local
    const float4 v = *(const float4*)(&W[(size_t)(k0 + r) * DIM + nb + c]);
    tile[r][c + 0] = v.x; tile[r][c + 1] = v.y;
    tile[r][c + 2] = v.z; tile[r][c + 3] = v.w;
  }
  __syncthreads();
  {
    const int nl = t >> 3;           // n-local
    const int kl = (t & 7) * 4;      // k-local
    ushort4 o;
    o.x = f2bf(tile[kl + 0][nl]); o.y = f2bf(tile[kl + 1][nl]);
    o.z = f2bf(tile[kl + 2][nl]); o.w = f2bf(tile[kl + 3][nl]);
    *(ushort4*)(&Wt[(size_t)(n0 + nl) * DIM + k0 + kl]) = o;
  }
}

// ---------------------------------------------------------------------------
// K1: fused MFMA GEMM + head-score epilogue.
// Grid 256 blocks x 512 threads. Block (bm, isR): 64 rows x 256 cols of
// (isR ? fr : fl). 8 waves, one head (32 cols) each; 16x16x32 bf16 MFMA.
// fl is never written to global: its only consumer is msl (computed here).
// ---------------------------------------------------------------------------
__global__ __launch_bounds__(512) void k_gemm_fused(
    const float* __restrict__ A, const unsigned short* __restrict__ Wt,
    const float* __restrict__ a_l, const float* __restrict__ a_r,
    float* __restrict__ fr, float* __restrict__ sr,
    float* __restrict__ msl, float* __restrict__ msr) {
  __shared__ unsigned short As[64 * 32];    // 4 KB
  __shared__ unsigned short Bs[256 * 32];   // 16 KB
  __shared__ float red[64][8];              // per-row per-head sums

  const int bid = blockIdx.x;
  const int isR = bid & 1;
  const int bm  = bid >> 1;       // 128 row tiles of 64
  const int m0 = bm * 64;
  const int n0 = isR * 256;       // Wt row offset (0: W_l, 256: W_r)

  const int t = threadIdx.x;
  const int lane = t & 63;
  const int wid = t >> 6;         // wave = head 0..7 (cols wid*32..+32)

  f32x4 acc[4][2];
  #pragma unroll
  for (int i = 0; i < 4; ++i)
    #pragma unroll
    for (int j = 0; j < 2; ++j) acc[i][j] = (f32x4){0.f, 0.f, 0.f, 0.f};

  for (int k0 = 0; k0 < DIM; k0 += 32) {
    if (t < 256) {
      const int row = t >> 2;
      const int kc = t & 3;
      const int slot = kc ^ ((row >> 1) & 3);
      const float4 a0 = *(const float4*)(&A[(size_t)(m0 + row) * DIM + k0 + kc * 8]);
      const float4 a1 = *(const float4*)(&A[(size_t)(m0 + row) * DIM + k0 + kc * 8 + 4]);
      u16x8 pa;
      pa[0] = f2bf(a0.x); pa[1] = f2bf(a0.y); pa[2] = f2bf(a0.z); pa[3] = f2bf(a0.w);
      pa[4] = f2bf(a1.x); pa[5] = f2bf(a1.y); pa[6] = f2bf(a1.z); pa[7] = f2bf(a1.w);
      *(u16x8*)((char*)As + row * 64 + slot * 16) = pa;
    }
    #pragma unroll
    for (int p = 0; p < 2; ++p) {
      const int task = t + p * 512;
      const int row = task >> 2;      // 0..255
      const int kc = task & 3;
      const int slot = kc ^ ((row >> 1) & 3);
      const u16x8 pb = *(const u16x8*)(&Wt[(size_t)(n0 + row) * DIM + k0 + kc * 8]);
      *(u16x8*)((char*)Bs + row * 64 + slot * 16) = pb;
    }
    __syncthreads();

    bf16x8 af[4], bfr[2];
    #pragma unroll
    for (int mr = 0; mr < 4; ++mr) {
      const int ra = mr * 16 + (lane & 15);
      const int sl = (lane >> 4) ^ ((ra >> 1) & 3);
      af[mr] = *(const bf16x8*)((const char*)As + ra * 64 + sl * 16);
    }
    #pragma unroll
    for (int nr = 0; nr < 2; ++nr) {
      const int cb = wid * 32 + nr * 16 + (lane & 15);
      const int sl = (lane >> 4) ^ ((cb >> 1) & 3);
      bfr[nr] = *(const bf16x8*)((const char*)Bs + cb * 64 + sl * 16);
    }
    #pragma unroll
    for (int mr = 0; mr < 4; ++mr)
      #pragma unroll
      for (int nr = 0; nr < 2; ++nr)
        acc[mr][nr] = __builtin_amdgcn_mfma_f32_16x16x32_bf16(af[mr], bfr[nr], acc[mr][nr], 0, 0, 0);
    __syncthreads();
  }

  // epilogue: per-head score sums. C/D: col=lane&15, row=(lane>>4)*4+r.
  const float* av = isR ? a_r : a_l;
  const int b = m0 >> 12;
  const int nbase = m0 & 4095;

  #pragma unroll
  for (int mr = 0; mr < 4; ++mr) {
    #pragma unroll
    for (int r = 0; r < 4; ++r) {
      float p = 0.f;
      #pragma unroll
      for (int nr = 0; nr < 2; ++nr) {
        float x = acc[mr][nr][r];
        x = x >= 0.f ? x : 0.01f * x;
        p = fmaf(x, av[nr * 16 + (lane & 15)], p);
      }
      #pragma unroll
      for (int o = 1; o < 16; o <<= 1) p += __shfl_xor(p, o, 16);
      if ((lane & 15) == 0) {
        const int rl = mr * 16 + (lane >> 4) * 4 + r;
        red[rl][wid] = p;
        if (isR) sr[((size_t)(b * HEADS + wid)) * SEQ + nbase + rl] = p;
      }
    }
  }
  __syncthreads();
  if (t < 64) {
    float s = 0.f;
    #pragma unroll
    for (int h2 = 0; h2 < 8; ++h2) s += red[t][h2];
    (isR ? msr : msl)[m0 + t] = s * 0.125f;
  }
  if (isR) {
    #pragma unroll
    for (int mr = 0; mr < 4; ++mr)
      #pragma unroll
      for (int nr = 0; nr < 2; ++nr) {
        const int col = wid * 32 + nr * 16 + (lane & 15);
        #pragma unroll
        for (int r = 0; r < 4; ++r) {
          const int row = m0 + mr * 16 + (lane >> 4) * 4 + r;
          fr[(size_t)row * DIM + col] = acc[mr][nr][r];
        }
      }
  }
}

// ---------------------------------------------------------------------------
// K2: unnormalized weighted context partials. Block (b, jc): 32 j's.
// w_hj = exp(sr[b,h,j]) (scores bounded ~±1.5, no max-shift needed).
// cpart[(b*128+jc)][t] = sum_jj w[t/32][jj] * fr[b, j0+jj, t]  (coalesced)
// wpart[(b*128+jc)][h] = sum_jj w[h][jj]
// ---------------------------------------------------------------------------
__global__ __launch_bounds__(256) void k_ctx(const float* __restrict__ sr,
                                             const float* __restrict__ fr,
                                             float* __restrict__ cpart,
                                             float* __restrict__ wpart) {
  const int b  = blockIdx.x >> 7;
  const int jc = blockIdx.x & 127;
  const int j0 = jc * JCHUNK;
  const int t = threadIdx.x;
  __shared__ float ws_[HEADS][JCHUNK];

  {
    const int h2 = t >> 5, jj = t & 31;
    float e = expf(sr[((size_t)(b * HEADS + h2)) * SEQ + j0 + jj]);
    ws_[h2][jj] = e;
    float s = e;
    #pragma unroll
    for (int o = 16; o > 0; o >>= 1) s += __shfl_xor(s, o, 32);
    if (jj == 0) wpart[(size_t)(b * NCHUNK + jc) * HEADS + h2] = s;
  }
  __syncthreads();

  const int h2 = t >> 5;
  const float* frb = fr + (size_t)(b * SEQ + j0) * DIM + t;
  float accv = 0.f;
  #pragma unroll 8
  for (int jj = 0; jj < JCHUNK; ++jj)
    accv = fmaf(ws_[h2][jj], frb[(size_t)jj * DIM], accv);
  cpart[(size_t)(b * NCHUNK + jc) * DIM + t] = accv;
}

// ---------------------------------------------------------------------------
// K3: reduce partials, normalize, partial matvec with W_final.
// Block (b, head kc): c[kc*32..+32] = sum_jc cpart / sum_jc wpart;
// fhp[(b*8+kc)][n] = sum_{kl<32} c[kl] * Wf[kc*32+kl][n].
// ---------------------------------------------------------------------------
__global__ __launch_bounds__(256) void k_fh(const float* __restrict__ cpart,
                                            const float* __restrict__ wpart,
                                            const float* __restrict__ Wf,
                                            float* __restrict__ fhp) {
  const int b = blockIdx.x >> 3;
  const int kc = blockIdx.x & 7;     // head / k-chunk
  const int t = threadIdx.x;
  __shared__ float credu[8][32];
  __shared__ float c_s[32];
  __shared__ float wred[128];

  // reduce cpart over 128 chunks for k in [kc*32, kc*32+32)
  {
    const int jg = t >> 5, kl = t & 31;
    float p = 0.f;
    #pragma unroll
    for (int jc = jg; jc < NCHUNK; jc += 8)
      p += cpart[(size_t)(b * NCHUNK + jc) * DIM + kc * HDIM + kl];
    credu[jg][kl] = p;
  }
  // reduce wpart over 128 chunks for head kc
  if (t < 128) wred[t] = wpart[(size_t)(b * NCHUNK + t) * HEADS + kc];
  __syncthreads();
  if (t < 32) {
    float s = 0.f;
    #pragma unroll
    for (int g2 = 0; g2 < 8; ++g2) s += credu[g2][t];
    // wsum reduce (scalar, every lane redundantly)
    float wsum = 0.f;
    #pragma unroll
    for (int i = 0; i < 128; ++i) wsum += wred[i];
    c_s[t] = s / wsum;
  }
  __syncthreads();

  float a2 = 0.f;
  #pragma unroll 8
  for (int kl = 0; kl < HDIM; ++kl)
    a2 = fmaf(c_s[kl], Wf[(size_t)(kc * HDIM + kl) * DIM + t], a2);
  fhp[(size_t)(b * HEADS + kc) * DIM + t] = a2;
}

// ---------------------------------------------------------------------------
// K4: fused LayerNorm(h + sum_p fhp) -> out  and attn outer-sum -> out tail.
// ---------------------------------------------------------------------------
__global__ __launch_bounds__(256) void k_ln_attn(const float* __restrict__ h,
                                                 const float* __restrict__ fhp,
                                                 const float* __restrict__ g,
                                                 const float* __restrict__ bb,
                                                 const float* __restrict__ msl,
                                                 const float* __restrict__ msr,
                                                 float* __restrict__ out,
                                                 float* __restrict__ attn) {
  const int row = blockIdx.x;
  const int b = row >> 12;
  const int t = threadIdx.x;
  float fh = 0.f;
  #pragma unroll
  for (int h2 = 0; h2 < 8; ++h2) fh += fhp[(size_t)(b * HEADS + h2) * DIM + t];
  const float x = h[(size_t)row * DIM + t] + fh;
  float s1 = x, s2 = x * x;
  #pragma unroll
  for (int o = 32; o > 0; o >>= 1) {
    s1 += __shfl_xor(s1, o, 64);
    s2 += __shfl_xor(s2, o, 64);
  }
  __shared__ float r1[4], r2[4];
  if ((t & 63) == 0) { r1[t >> 6] = s1; r2[t >> 6] = s2; }
  __syncthreads();
  s1 = r1[0] + r1[1] + r1[2] + r1[3];
  s2 = r2[0] + r2[1] + r2[2] + r2[3];
  const float mu = s1 * (1.f / 256.f);
  const float var = s2 * (1.f / 256.f) - mu * mu;
  const float rs = rsqrtf(var + 1e-5f);
  out[(size_t)row * DIM + t] = (x - mu) * rs * g[t] + bb[t];

  const float v = msl[row];
  const f32x4* mr4 = (const f32x4*)(msr + ((size_t)b << 12));
  f32x4* dst = (f32x4*)(attn + ((size_t)row << 12));
  #pragma unroll
  for (int q = 0; q < 4; ++q) {
    f32x4 m4 = mr4[q * 256 + t];
    __builtin_nontemporal_store(m4 + v, &dst[q * 256 + t]);
  }
}

// ---------------------------------------------------------------------------
extern "C" void kernel_launch(void* const* d_in, const int* in_sizes, int n_in,
                              void* d_out, int out_size, void* d_ws, size_t ws_size,
                              hipStream_t stream) {
  const float* h  = (const float*)d_in[0];
  const float* Wl = (const float*)d_in[1];
  const float* Wr = (const float*)d_in[2];
  const float* al = (const float*)d_in[3];
  const float* ar = (const float*)d_in[4];
  const float* Wf = (const float*)d_in[5];
  const float* g  = (const float*)d_in[6];
  const float* bb = (const float*)d_in[7];
  float* out = (float*)d_out;
  float* ws  = (float*)d_ws;

  float* fr    = ws;                                 // 2,097,152 f32
  float* srs   = fr + (size_t)M_ROWS * DIM;          // 65,536
  float* msl   = srs + BATCH * HEADS * SEQ;          // 8,192
  float* msr   = msl + M_ROWS;                       // 8,192
  float* cpart = msr + M_ROWS;                       // B*128*256 = 65,536
  float* wpart = cpart + BATCH * NCHUNK * DIM;       // B*128*8 = 2,048
  float* fhp   = wpart + BATCH * NCHUNK * HEADS;     // 4,096
  unsigned short* Wt = (unsigned short*)(fhp + BATCH * HEADS * DIM);

  k_prep<<<dim3(8, 16), 256, 0, stream>>>(Wl, Wr, Wt);
  k_gemm_fused<<<256, 512, 0, stream>>>(h, Wt, al, ar, fr, srs, msl, msr);
  k_ctx<<<BATCH * NCHUNK, 256, 0, stream>>>(srs, fr, cpart, wpart);
  k_fh<<<BATCH * HEADS, 256, 0, stream>>>(cpart, wpart, Wf, fhp);
  k_ln_attn<<<M_ROWS, 256, 0, stream>>>(h, fhp, g, bb, msl, msr,
                                        out, out + (size_t)M_ROWS * DIM);
}